// Round 11
// baseline (255.339 us; speedup 1.0000x reference)
//
#include <hip/hip_runtime.h>

#define BLOCK 256
#define WPB 4                    // waves per block; each owns a quarter-row
#define C_DIM 10000
#define C4 (C_DIM / 4)           // 2500 float4s per row
#define SEGQ (C4 / WPB)          // 625 float4s per wave
#define ITQ ((SEGQ + 63) / 64)   // 10 staged iterations per wave
#define NIT4 ((C4 + 63) / 64)    // 40 (full-row fallback only)
#define TAU 1.0f
#define CAP 512                  // per-wave candidate cap (mean ~57 at PIV_HI)
#define PIV_HI 2.0f
#define PIV_LO 1.0f

// Monotone bijection float -> uint32 (larger float => larger key)
__device__ __forceinline__ unsigned flip_key(float f) {
    unsigned u = __float_as_uint(f);
    return (u & 0x80000000u) ? ~u : (u | 0x80000000u);
}
__device__ __forceinline__ float unflip_key(unsigned k) {
    unsigned u = (k & 0x80000000u) ? (k & 0x7fffffffu) : ~k;
    return __uint_as_float(u);
}
// # of set bits in m strictly below my lane (64-lane)
__device__ __forceinline__ int mbcnt64(unsigned long long m) {
    return (int)__builtin_amdgcn_mbcnt_hi((unsigned)(m >> 32),
               __builtin_amdgcn_mbcnt_lo((unsigned)(m & 0xffffffffu), 0u));
}
// Async global->LDS, 16B per lane. LDS dest = uniform base + lane*16 (HW rule).
__device__ __forceinline__ void gload16(const void* g, void* l) {
    __builtin_amdgcn_global_load_lds(
        (const __attribute__((address_space(1))) unsigned*)g,
        (__attribute__((address_space(3))) unsigned*)l, 16, 0, 0);
}

__global__ void zero_out_kernel(float* out, int n) {
    int i = blockIdx.x * blockDim.x + threadIdx.x;
    if (i < n) out[i] = 0.f;
}

// Wave-uniform radix bin pick: each lane owns 4 bins (hv), suffix-scan across
// the wave, exactly one lane picks; result broadcast via shuffles. No barrier.
__device__ __forceinline__ void wave_pick(uint4 hv, int lane, int shift,
                                          unsigned& prefix, unsigned& kr, unsigned& cnt) {
    unsigned loc = hv.x + hv.y + hv.z + hv.w;
    unsigned suf = loc;
    #pragma unroll
    for (int off = 1; off < 64; off <<= 1) {
        unsigned o = (unsigned)__shfl_down((int)suf, off);
        if (lane + off < 64) suf += o;
    }
    unsigned sufex = suf - loc;              // candidates in bins strictly above my 4
    unsigned s3 = sufex + hv.w;
    unsigned s2 = s3 + hv.z;
    unsigned s1 = s2 + hv.y;
    unsigned s0 = s1 + hv.x;
    int bsel = -1; unsigned nkr = 0u, ncnt = 0u;
    if      (s3 >= kr && s3 - hv.w < kr) { bsel = 4 * lane + 3; nkr = kr - (s3 - hv.w); ncnt = hv.w; }
    else if (s2 >= kr && s2 - hv.z < kr) { bsel = 4 * lane + 2; nkr = kr - (s2 - hv.z); ncnt = hv.z; }
    else if (s1 >= kr && s1 - hv.y < kr) { bsel = 4 * lane + 1; nkr = kr - (s1 - hv.y); ncnt = hv.y; }
    else if (s0 >= kr && s0 - hv.x < kr) { bsel = 4 * lane + 0; nkr = kr - (s0 - hv.x); ncnt = hv.x; }
    unsigned long long pm = __ballot(bsel >= 0);
    int src = __ffsll((unsigned long long)pm) - 1;   // exactly one lane picked
    prefix |= ((unsigned)__shfl(bsel, src)) << shift;
    kr  = (unsigned)__shfl((int)nkr, src);
    cnt = (unsigned)__shfl((int)ncnt, src);
}

// Block per row; 4 waves sweep their quarter-row via DOUBLE-BUFFERED
// global_load_lds staging (no VGPR payload -> low VGPR + continuous loads).
// Counted s_waitcnt vmcnt(2): next-iter prefetch stays in flight across the
// wait (never drain to 0 mid-loop). Wave-private buffers -> no extra barriers.
// LESSON (R6/R9): launch_bounds floors >4 force VGPR caps -> scratch spills.
// LESSON (R10): the ~1.7 TB/s wall is the VGPR-return load path, not HBM/L3;
// gload_lds bypasses it.
__global__ __launch_bounds__(BLOCK, 4) void topk_la_loss_kernel(
    const float* __restrict__ logit, const int* __restrict__ target,
    const float* __restrict__ lcn, const int* __restrict__ kpc,
    float* __restrict__ out, int B) {
    __shared__ unsigned candk[WPB][CAP];         // per-wave private segments
    __shared__ unsigned short candi[WPB][CAP];
    __shared__ float4 stg[WPB][2][2][64];        // [wave][buf][f/l][lane] 16KB
    __shared__ unsigned hist[256];               // wave 0 only
    __shared__ unsigned sh_nb[WPB];
    __shared__ float red_a[WPB], red_b[WPB];
    __shared__ float sh_thresh;

    const int tid = threadIdx.x;
    const int lane = tid & 63;
    const int wid = tid >> 6;
    const int row = blockIdx.x;
    const float* lrow = logit + (size_t)row * C_DIM;
    const float4* lrow4 = (const float4*)lrow;
    const float4* lcn4 = (const float4*)lcn;

    const int t = target[row];                   // uniform (broadcast) loads
    int k = kpc[t]; if (k > C_DIM) k = C_DIM;
    const float logit_t = lrow[t];               // hoisted: hides tail latency
    const float lcn_t = lcn[t];

    unsigned* ck = candk[wid];
    unsigned short* ci = candi[wid];
    const int base4 = wid * SEGQ;                // this wave's quarter (float4 units)

    float z0 = 0.f, z1 = 0.f, z2 = 0.f, z3 = 0.f;
    float mA = -__builtin_inff(), mB = -__builtin_inff();
    unsigned nb = 0u;

    // ---- prologue: stage it=0 into buf 0 (all 64 lanes active: 64 <= SEGQ)
    gload16(&lrow4[base4 + lane], &stg[wid][0][0][0]);
    gload16(&lcn4[base4 + lane], &stg[wid][0][1][0]);

    #pragma unroll
    for (int it = 0; it < ITQ; ++it) {
        const int cur = it & 1, nxt = cur ^ 1;
        if (it + 1 < ITQ) {                      // issue next-iter staging
            const int j4n = (it + 1) * 64 + lane;
            if (j4n < SEGQ) {                    // divergent only at it+1==9
                gload16(&lrow4[base4 + j4n], &stg[wid][nxt][0][0]);
                gload16(&lcn4[base4 + j4n], &stg[wid][nxt][1][0]);
            }
            // oldest 2 (cur buf) must land; newest 2 (nxt buf) stay in flight
            asm volatile("s_waitcnt vmcnt(2)" ::: "memory");
        } else {
            asm volatile("s_waitcnt vmcnt(0)" ::: "memory");
        }
        __builtin_amdgcn_sched_barrier(0);       // pin LDS reads after the wait
        const int j4l = it * 64 + lane;
        float4 f, l;
        if (j4l < SEGQ) {
            f = stg[wid][cur][0][lane];
            l = stg[wid][cur][1][lane];
        } else {                                 // pad lanes (it==9, lane>=49)
            f = make_float4(-1e30f, -1e30f, -1e30f, -1e30f);
            l = make_float4(0.f, 0.f, 0.f, 0.f);
        }
        const float a0 = f.x + TAU * l.x, a1 = f.y + TAU * l.y;
        const float a2 = f.z + TAU * l.z, a3 = f.w + TAU * l.w;
        z0 += __expf(a0); z1 += __expf(a1);      // exp(-1e30)=0 for pad lanes
        z2 += __expf(a2); z3 += __expf(a3);
        mA = fmaxf(mA, fmaxf(a0, a1));
        mB = fmaxf(mB, fmaxf(a2, a3));
        const int j = 4 * (base4 + j4l);
        unsigned long long m;
        m = __ballot(f.x >= PIV_HI);
        if (f.x >= PIV_HI) { unsigned p = nb + (unsigned)mbcnt64(m); if (p < CAP) { ck[p] = __float_as_uint(f.x); ci[p] = (unsigned short)(j + 0); } }
        nb += (unsigned)__popcll(m);
        m = __ballot(f.y >= PIV_HI);
        if (f.y >= PIV_HI) { unsigned p = nb + (unsigned)mbcnt64(m); if (p < CAP) { ck[p] = __float_as_uint(f.y); ci[p] = (unsigned short)(j + 1); } }
        nb += (unsigned)__popcll(m);
        m = __ballot(f.z >= PIV_HI);
        if (f.z >= PIV_HI) { unsigned p = nb + (unsigned)mbcnt64(m); if (p < CAP) { ck[p] = __float_as_uint(f.z); ci[p] = (unsigned short)(j + 2); } }
        nb += (unsigned)__popcll(m);
        m = __ballot(f.w >= PIV_HI);
        if (f.w >= PIV_HI) { unsigned p = nb + (unsigned)mbcnt64(m); if (p < CAP) { ck[p] = __float_as_uint(f.w); ci[p] = (unsigned short)(j + 3); } }
        nb += (unsigned)__popcll(m);
    }

    float z = (z0 + z1) + (z2 + z3);
    float madj = fmaxf(mA, mB);
    #pragma unroll
    for (int off = 32; off; off >>= 1) madj = fmaxf(madj, __shfl_xor(madj, off));
    if (lane == 0) { red_a[wid] = madj; sh_nb[wid] = nb; }
    __syncthreads();                             // ---- B1

    const float madjB = fmaxf(fmaxf(red_a[0], red_a[1]), fmaxf(red_a[2], red_a[3]));
    unsigned nbs0 = sh_nb[0], nbs1 = sh_nb[1], nbs2 = sh_nb[2], nbs3 = sh_nb[3];
    unsigned ntot = nbs0 + nbs1 + nbs2 + nbs3;
    unsigned nmax = max(max(nbs0, nbs1), max(nbs2, nbs3));
    int path = (ntot >= (unsigned)k && nmax <= CAP) ? 0 : ((ntot < (unsigned)k) ? 1 : 2);

    // ---- Rare: too few candidates at PIV_HI -> recompact own quarter at PIV_LO
    if (path == 1) {
        nb = 0u;
        for (int it = 0; it < ITQ; ++it) {
            const int j4l = it * 64 + lane;
            float4 f;
            if (j4l < SEGQ) f = lrow4[base4 + j4l];
            else f = make_float4(-1e30f, -1e30f, -1e30f, -1e30f);
            const int j = 4 * (base4 + j4l);
            unsigned long long m;
            m = __ballot(f.x >= PIV_LO);
            if (f.x >= PIV_LO) { unsigned p = nb + (unsigned)mbcnt64(m); if (p < CAP) { ck[p] = __float_as_uint(f.x); ci[p] = (unsigned short)(j + 0); } }
            nb += (unsigned)__popcll(m);
            m = __ballot(f.y >= PIV_LO);
            if (f.y >= PIV_LO) { unsigned p = nb + (unsigned)mbcnt64(m); if (p < CAP) { ck[p] = __float_as_uint(f.y); ci[p] = (unsigned short)(j + 1); } }
            nb += (unsigned)__popcll(m);
            m = __ballot(f.z >= PIV_LO);
            if (f.z >= PIV_LO) { unsigned p = nb + (unsigned)mbcnt64(m); if (p < CAP) { ck[p] = __float_as_uint(f.z); ci[p] = (unsigned short)(j + 2); } }
            nb += (unsigned)__popcll(m);
            m = __ballot(f.w >= PIV_LO);
            if (f.w >= PIV_LO) { unsigned p = nb + (unsigned)mbcnt64(m); if (p < CAP) { ck[p] = __float_as_uint(f.w); ci[p] = (unsigned short)(j + 3); } }
            nb += (unsigned)__popcll(m);
        }
        if (lane == 0) sh_nb[wid] = nb;
        __syncthreads();                         // B1a (cold path only)
        nbs0 = sh_nb[0]; nbs1 = sh_nb[1]; nbs2 = sh_nb[2]; nbs3 = sh_nb[3];
        ntot = nbs0 + nbs1 + nbs2 + nbs3;
        nmax = max(max(nbs0, nbs1), max(nbs2, nbs3));
        path = (ntot >= (unsigned)k && nmax <= CAP) ? 0 : 2;
    }

    // ---- Select: wave 0 alone, fully wave-synchronous (no barriers inside)
    if (path == 0) {
        if (wid == 0) {
            // Exact byte-radix select among ntot candidates across 4 segments
            // (all >= PIV > 0 -> raw float bits order like uints).
            unsigned prefix = 0u, kr = (unsigned)k, cnt = ntot, kmask = 0u;
            const unsigned nbs[4] = {nbs0, nbs1, nbs2, nbs3};
            for (int q = 0; q < 4; ++q) {
                if (cnt == 1u) break;            // wave-uniform
                const int shift = 24 - 8 * q;
                *(uint4*)&hist[4 * lane] = make_uint4(0u, 0u, 0u, 0u);
                #pragma unroll
                for (int s = 0; s < 4; ++s) {
                    for (int i = lane; i < (int)nbs[s]; i += 64) {
                        unsigned kk = candk[s][i];
                        if ((kk & kmask) == prefix) atomicAdd(&hist[(kk >> shift) & 0xFFu], 1u);
                    }
                }
                uint4 hv = *(const uint4*)&hist[4 * lane];
                wave_pick(hv, lane, shift, prefix, kr, cnt);
                kmask |= (0xFFu << shift);
            }
            if (cnt == 1u && kmask != 0xFFFFFFFFu) {   // unique survivor: full bits
                unsigned found = 0u;
                #pragma unroll
                for (int s = 0; s < 4; ++s) {
                    for (int i = lane; i < (int)nbs[s]; i += 64) {
                        unsigned kk = candk[s][i];
                        if ((kk & kmask) == prefix) found = kk;
                    }
                }
                #pragma unroll
                for (int off = 32; off; off >>= 1) found |= (unsigned)__shfl_xor((int)found, off);
                prefix = found;
            }
            if (lane == 0) sh_thresh = __uint_as_float(prefix);
        }
    } else {
        // Generic fallback (never hot): wave 0 full-row radix on flipped keys
        if (wid == 0) {
            unsigned prefix = 0u, kr = (unsigned)k, cnt = 0u;
            for (int p = 0; p < 4; ++p) {
                const int shift = 24 - 8 * p;
                const unsigned pmask = p ? (0xFFFFFFFFu << (shift + 8)) : 0u;
                *(uint4*)&hist[4 * lane] = make_uint4(0u, 0u, 0u, 0u);
                for (int it = 0; it < NIT4; ++it) {
                    const int j4 = it * 64 + lane;
                    if (j4 < C4) {
                        float4 f = lrow4[j4];
                        unsigned kk;
                        kk = flip_key(f.x); if ((kk & pmask) == prefix) atomicAdd(&hist[(kk >> shift) & 0xFFu], 1u);
                        kk = flip_key(f.y); if ((kk & pmask) == prefix) atomicAdd(&hist[(kk >> shift) & 0xFFu], 1u);
                        kk = flip_key(f.z); if ((kk & pmask) == prefix) atomicAdd(&hist[(kk >> shift) & 0xFFu], 1u);
                        kk = flip_key(f.w); if ((kk & pmask) == prefix) atomicAdd(&hist[(kk >> shift) & 0xFFu], 1u);
                    }
                }
                uint4 hv = *(const uint4*)&hist[4 * lane];
                wave_pick(hv, lane, shift, prefix, kr, cnt);
            }
            if (lane == 0) sh_thresh = unflip_key(prefix);
        }
    }
    __syncthreads();                             // ---- B2
    const float thresh = sh_thresh;

    const bool rare = fabsf(madjB) > 80.f;       // exp(adj) over/underflow guard
    float sm = 0.f;
    if (!rare) {
        if (path == 0) {
            // masked set is a subset of this wave's own candidates
            const int nc = (int)sh_nb[wid];
            for (int i = lane; i < nc; i += 64) {
                const float v = __uint_as_float(ck[i]);
                if (v >= thresh) sm += __expf(v + TAU * lcn[ci[i]]);
            }
        } else {
            for (int it = 0; it < ITQ; ++it) {
                const int j4l = it * 64 + lane;
                if (j4l < SEGQ) {
                    float4 f = lrow4[base4 + j4l];
                    float4 l = lcn4[base4 + j4l];
                    if (f.x >= thresh) sm += __expf(f.x + TAU * l.x);
                    if (f.y >= thresh) sm += __expf(f.y + TAU * l.y);
                    if (f.z >= thresh) sm += __expf(f.z + TAU * l.z);
                    if (f.w >= thresh) sm += __expf(f.w + TAU * l.w);
                }
            }
        }
    } else {
        // exact re-sweep of own quarter with max subtraction (never hot)
        z = 0.f;
        for (int it = 0; it < ITQ; ++it) {
            const int j4l = it * 64 + lane;
            if (j4l < SEGQ) {
                float4 f = lrow4[base4 + j4l];
                float4 l = lcn4[base4 + j4l];
                float e;
                e = __expf(f.x + TAU * l.x - madjB); z += e; if (f.x >= thresh) sm += e;
                e = __expf(f.y + TAU * l.y - madjB); z += e; if (f.y >= thresh) sm += e;
                e = __expf(f.z + TAU * l.z - madjB); z += e; if (f.z >= thresh) sm += e;
                e = __expf(f.w + TAU * l.w - madjB); z += e; if (f.w >= thresh) sm += e;
            }
        }
    }

    // ---- Joint reduction of z, sm: wave-level shuffles, then 4 values via LDS
    #pragma unroll
    for (int off = 32; off; off >>= 1) {
        z  += __shfl_down(z, off);
        sm += __shfl_down(sm, off);
    }
    if (lane == 0) { red_a[wid] = z; red_b[wid] = sm; }
    __syncthreads();                             // ---- B3

    if (tid == 0) {
        const float Z = red_a[0] + red_a[1] + red_a[2] + red_a[3];
        const float S = red_b[0] + red_b[1] + red_b[2] + red_b[3];
        const float adj_t = logit_t + TAU * lcn_t;
        const float sub = rare ? madjB : 0.f;
        const float lpt = adj_t - sub - __logf(Z);             // log_p_adj[target]
        const float p_num = ((logit_t >= thresh) ? __expf(lpt) : 0.f) + 1e-6f;
        const float Smask = S / Z + (float)C_DIM * 1e-6f;
        const float loss = 0.5f * (-lpt + __logf(Smask) - __logf(p_num));
        atomicAdd(out, loss / (float)B);
    }
}

extern "C" void kernel_launch(void* const* d_in, const int* in_sizes, int n_in,
                              void* d_out, int out_size, void* d_ws, size_t ws_size,
                              hipStream_t stream) {
    const float* logit  = (const float*)d_in[0];
    const int*   target = (const int*)d_in[1];
    const float* lcn    = (const float*)d_in[2];
    const int*   kpc    = (const int*)d_in[3];
    float* out = (float*)d_out;
    const int B = in_sizes[1];   // target is [B]

    zero_out_kernel<<<1, 64, 0, stream>>>(out, out_size);
    topk_la_loss_kernel<<<B, BLOCK, 0, stream>>>(logit, target, lcn, kpc, out, B);
}

// Round 12
// 254.632 us; speedup vs baseline: 1.0028x; 1.0028x over previous
//
#include <hip/hip_runtime.h>

#define BLOCK 256
#define WPB 4                    // waves per block; each owns a quarter-row
#define C_DIM 10000
#define C4 (C_DIM / 4)           // 2500 float4s per row
#define SEGQ (C4 / WPB)          // 625 float4s per wave
#define ITQ ((SEGQ + 63) / 64)   // 10 staged iterations per wave
#define NIT4 ((C4 + 63) / 64)    // 40 (full-row fallback only)
#define TAU 1.0f
#define CAP 512                  // per-wave candidate cap (mean ~57 at PIV_HI)
#define PIV_HI 2.0f
#define PIV_LO 1.0f
#define NSLOT 256                // partial-sum slots (line-padded, stride 16 floats)
#define SLOT_STRIDE 16           // 64B: one slot per cache line

// Monotone bijection float -> uint32 (larger float => larger key)
__device__ __forceinline__ unsigned flip_key(float f) {
    unsigned u = __float_as_uint(f);
    return (u & 0x80000000u) ? ~u : (u | 0x80000000u);
}
__device__ __forceinline__ float unflip_key(unsigned k) {
    unsigned u = (k & 0x80000000u) ? (k & 0x7fffffffu) : ~k;
    return __uint_as_float(u);
}
// # of set bits in m strictly below my lane (64-lane)
__device__ __forceinline__ int mbcnt64(unsigned long long m) {
    return (int)__builtin_amdgcn_mbcnt_hi((unsigned)(m >> 32),
               __builtin_amdgcn_mbcnt_lo((unsigned)(m & 0xffffffffu), 0u));
}
// Async global->LDS, 16B per lane. LDS dest = uniform base + lane*16 (HW rule).
__device__ __forceinline__ void gload16(const void* g, void* l) {
    __builtin_amdgcn_global_load_lds(
        (const __attribute__((address_space(1))) unsigned*)g,
        (__attribute__((address_space(3))) unsigned*)l, 16, 0, 0);
}

// Zero the output AND the partial-sum slots (ws) each iteration.
__global__ void zero_out_kernel(float* out, int n, float* part, int np) {
    int i = blockIdx.x * blockDim.x + threadIdx.x;
    if (i < n) out[i] = 0.f;
    if (part && i < np) part[i] = 0.f;
}

// Final reduction: 256 line-padded slots -> out[0]. One wave.
__global__ void reduce_out_kernel(const float* __restrict__ part, float* __restrict__ out) {
    const int lane = threadIdx.x;                // 64 threads
    float s = 0.f;
    #pragma unroll
    for (int i = lane; i < NSLOT; i += 64) s += part[i * SLOT_STRIDE];
    #pragma unroll
    for (int off = 32; off; off >>= 1) s += __shfl_down(s, off);
    if (lane == 0) out[0] = s;
}

// Wave-uniform radix bin pick: each lane owns 4 bins (hv), suffix-scan across
// the wave, exactly one lane picks; result broadcast via shuffles. No barrier.
__device__ __forceinline__ void wave_pick(uint4 hv, int lane, int shift,
                                          unsigned& prefix, unsigned& kr, unsigned& cnt) {
    unsigned loc = hv.x + hv.y + hv.z + hv.w;
    unsigned suf = loc;
    #pragma unroll
    for (int off = 1; off < 64; off <<= 1) {
        unsigned o = (unsigned)__shfl_down((int)suf, off);
        if (lane + off < 64) suf += o;
    }
    unsigned sufex = suf - loc;              // candidates in bins strictly above my 4
    unsigned s3 = sufex + hv.w;
    unsigned s2 = s3 + hv.z;
    unsigned s1 = s2 + hv.y;
    unsigned s0 = s1 + hv.x;
    int bsel = -1; unsigned nkr = 0u, ncnt = 0u;
    if      (s3 >= kr && s3 - hv.w < kr) { bsel = 4 * lane + 3; nkr = kr - (s3 - hv.w); ncnt = hv.w; }
    else if (s2 >= kr && s2 - hv.z < kr) { bsel = 4 * lane + 2; nkr = kr - (s2 - hv.z); ncnt = hv.z; }
    else if (s1 >= kr && s1 - hv.y < kr) { bsel = 4 * lane + 1; nkr = kr - (s1 - hv.y); ncnt = hv.y; }
    else if (s0 >= kr && s0 - hv.x < kr) { bsel = 4 * lane + 0; nkr = kr - (s0 - hv.x); ncnt = hv.x; }
    unsigned long long pm = __ballot(bsel >= 0);
    int src = __ffsll((unsigned long long)pm) - 1;   // exactly one lane picked
    prefix |= ((unsigned)__shfl(bsel, src)) << shift;
    kr  = (unsigned)__shfl((int)nkr, src);
    cnt = (unsigned)__shfl((int)ncnt, src);
}

// Block per row; 4 waves sweep their quarter-row via double-buffered
// global_load_lds staging, counted vmcnt(2). Epilogue: atomicAdd into a
// line-padded ws slot (row & 255) instead of ONE global address.
// THEORY (R11): 4096 same-address atomics serialize at ~57cy each = the
// ~98us floor every structure hit; 256 parallel lines cut that to ~1us.
__global__ __launch_bounds__(BLOCK, 4) void topk_la_loss_kernel(
    const float* __restrict__ logit, const int* __restrict__ target,
    const float* __restrict__ lcn, const int* __restrict__ kpc,
    float* __restrict__ out, float* __restrict__ part, int B) {
    __shared__ unsigned candk[WPB][CAP];         // per-wave private segments
    __shared__ unsigned short candi[WPB][CAP];
    __shared__ float4 stg[WPB][2][2][64];        // [wave][buf][f/l][lane] 16KB
    __shared__ unsigned hist[256];               // wave 0 only
    __shared__ unsigned sh_nb[WPB];
    __shared__ float red_a[WPB], red_b[WPB];
    __shared__ float sh_thresh;

    const int tid = threadIdx.x;
    const int lane = tid & 63;
    const int wid = tid >> 6;
    const int row = blockIdx.x;
    const float* lrow = logit + (size_t)row * C_DIM;
    const float4* lrow4 = (const float4*)lrow;
    const float4* lcn4 = (const float4*)lcn;

    const int t = target[row];                   // uniform (broadcast) loads
    int k = kpc[t]; if (k > C_DIM) k = C_DIM;
    const float logit_t = lrow[t];               // hoisted: hides tail latency
    const float lcn_t = lcn[t];

    unsigned* ck = candk[wid];
    unsigned short* ci = candi[wid];
    const int base4 = wid * SEGQ;                // this wave's quarter (float4 units)

    float z0 = 0.f, z1 = 0.f, z2 = 0.f, z3 = 0.f;
    float mA = -__builtin_inff(), mB = -__builtin_inff();
    unsigned nb = 0u;

    // ---- prologue: stage it=0 into buf 0 (all 64 lanes active: 64 <= SEGQ)
    gload16(&lrow4[base4 + lane], &stg[wid][0][0][0]);
    gload16(&lcn4[base4 + lane], &stg[wid][0][1][0]);

    #pragma unroll
    for (int it = 0; it < ITQ; ++it) {
        const int cur = it & 1, nxt = cur ^ 1;
        if (it + 1 < ITQ) {                      // issue next-iter staging
            const int j4n = (it + 1) * 64 + lane;
            if (j4n < SEGQ) {                    // divergent only at it+1==9
                gload16(&lrow4[base4 + j4n], &stg[wid][nxt][0][0]);
                gload16(&lcn4[base4 + j4n], &stg[wid][nxt][1][0]);
            }
            // oldest 2 (cur buf) must land; newest 2 (nxt buf) stay in flight
            asm volatile("s_waitcnt vmcnt(2)" ::: "memory");
        } else {
            asm volatile("s_waitcnt vmcnt(0)" ::: "memory");
        }
        __builtin_amdgcn_sched_barrier(0);       // pin LDS reads after the wait
        const int j4l = it * 64 + lane;
        float4 f, l;
        if (j4l < SEGQ) {
            f = stg[wid][cur][0][lane];
            l = stg[wid][cur][1][lane];
        } else {                                 // pad lanes (it==9, lane>=49)
            f = make_float4(-1e30f, -1e30f, -1e30f, -1e30f);
            l = make_float4(0.f, 0.f, 0.f, 0.f);
        }
        const float a0 = f.x + TAU * l.x, a1 = f.y + TAU * l.y;
        const float a2 = f.z + TAU * l.z, a3 = f.w + TAU * l.w;
        z0 += __expf(a0); z1 += __expf(a1);      // exp(-1e30)=0 for pad lanes
        z2 += __expf(a2); z3 += __expf(a3);
        mA = fmaxf(mA, fmaxf(a0, a1));
        mB = fmaxf(mB, fmaxf(a2, a3));
        const int j = 4 * (base4 + j4l);
        unsigned long long m;
        m = __ballot(f.x >= PIV_HI);
        if (f.x >= PIV_HI) { unsigned p = nb + (unsigned)mbcnt64(m); if (p < CAP) { ck[p] = __float_as_uint(f.x); ci[p] = (unsigned short)(j + 0); } }
        nb += (unsigned)__popcll(m);
        m = __ballot(f.y >= PIV_HI);
        if (f.y >= PIV_HI) { unsigned p = nb + (unsigned)mbcnt64(m); if (p < CAP) { ck[p] = __float_as_uint(f.y); ci[p] = (unsigned short)(j + 1); } }
        nb += (unsigned)__popcll(m);
        m = __ballot(f.z >= PIV_HI);
        if (f.z >= PIV_HI) { unsigned p = nb + (unsigned)mbcnt64(m); if (p < CAP) { ck[p] = __float_as_uint(f.z); ci[p] = (unsigned short)(j + 2); } }
        nb += (unsigned)__popcll(m);
        m = __ballot(f.w >= PIV_HI);
        if (f.w >= PIV_HI) { unsigned p = nb + (unsigned)mbcnt64(m); if (p < CAP) { ck[p] = __float_as_uint(f.w); ci[p] = (unsigned short)(j + 3); } }
        nb += (unsigned)__popcll(m);
    }

    float z = (z0 + z1) + (z2 + z3);
    float madj = fmaxf(mA, mB);
    #pragma unroll
    for (int off = 32; off; off >>= 1) madj = fmaxf(madj, __shfl_xor(madj, off));
    if (lane == 0) { red_a[wid] = madj; sh_nb[wid] = nb; }
    __syncthreads();                             // ---- B1

    const float madjB = fmaxf(fmaxf(red_a[0], red_a[1]), fmaxf(red_a[2], red_a[3]));
    unsigned nbs0 = sh_nb[0], nbs1 = sh_nb[1], nbs2 = sh_nb[2], nbs3 = sh_nb[3];
    unsigned ntot = nbs0 + nbs1 + nbs2 + nbs3;
    unsigned nmax = max(max(nbs0, nbs1), max(nbs2, nbs3));
    int path = (ntot >= (unsigned)k && nmax <= CAP) ? 0 : ((ntot < (unsigned)k) ? 1 : 2);

    // ---- Rare: too few candidates at PIV_HI -> recompact own quarter at PIV_LO
    if (path == 1) {
        nb = 0u;
        for (int it = 0; it < ITQ; ++it) {
            const int j4l = it * 64 + lane;
            float4 f;
            if (j4l < SEGQ) f = lrow4[base4 + j4l];
            else f = make_float4(-1e30f, -1e30f, -1e30f, -1e30f);
            const int j = 4 * (base4 + j4l);
            unsigned long long m;
            m = __ballot(f.x >= PIV_LO);
            if (f.x >= PIV_LO) { unsigned p = nb + (unsigned)mbcnt64(m); if (p < CAP) { ck[p] = __float_as_uint(f.x); ci[p] = (unsigned short)(j + 0); } }
            nb += (unsigned)__popcll(m);
            m = __ballot(f.y >= PIV_LO);
            if (f.y >= PIV_LO) { unsigned p = nb + (unsigned)mbcnt64(m); if (p < CAP) { ck[p] = __float_as_uint(f.y); ci[p] = (unsigned short)(j + 1); } }
            nb += (unsigned)__popcll(m);
            m = __ballot(f.z >= PIV_LO);
            if (f.z >= PIV_LO) { unsigned p = nb + (unsigned)mbcnt64(m); if (p < CAP) { ck[p] = __float_as_uint(f.z); ci[p] = (unsigned short)(j + 2); } }
            nb += (unsigned)__popcll(m);
            m = __ballot(f.w >= PIV_LO);
            if (f.w >= PIV_LO) { unsigned p = nb + (unsigned)mbcnt64(m); if (p < CAP) { ck[p] = __float_as_uint(f.w); ci[p] = (unsigned short)(j + 3); } }
            nb += (unsigned)__popcll(m);
        }
        if (lane == 0) sh_nb[wid] = nb;
        __syncthreads();                         // B1a (cold path only)
        nbs0 = sh_nb[0]; nbs1 = sh_nb[1]; nbs2 = sh_nb[2]; nbs3 = sh_nb[3];
        ntot = nbs0 + nbs1 + nbs2 + nbs3;
        nmax = max(max(nbs0, nbs1), max(nbs2, nbs3));
        path = (ntot >= (unsigned)k && nmax <= CAP) ? 0 : 2;
    }

    // ---- Select: wave 0 alone, fully wave-synchronous (no barriers inside)
    if (path == 0) {
        if (wid == 0) {
            // Exact byte-radix select among ntot candidates across 4 segments
            // (all >= PIV > 0 -> raw float bits order like uints).
            unsigned prefix = 0u, kr = (unsigned)k, cnt = ntot, kmask = 0u;
            const unsigned nbs[4] = {nbs0, nbs1, nbs2, nbs3};
            for (int q = 0; q < 4; ++q) {
                if (cnt == 1u) break;            // wave-uniform
                const int shift = 24 - 8 * q;
                *(uint4*)&hist[4 * lane] = make_uint4(0u, 0u, 0u, 0u);
                #pragma unroll
                for (int s = 0; s < 4; ++s) {
                    for (int i = lane; i < (int)nbs[s]; i += 64) {
                        unsigned kk = candk[s][i];
                        if ((kk & kmask) == prefix) atomicAdd(&hist[(kk >> shift) & 0xFFu], 1u);
                    }
                }
                uint4 hv = *(const uint4*)&hist[4 * lane];
                wave_pick(hv, lane, shift, prefix, kr, cnt);
                kmask |= (0xFFu << shift);
            }
            if (cnt == 1u && kmask != 0xFFFFFFFFu) {   // unique survivor: full bits
                unsigned found = 0u;
                #pragma unroll
                for (int s = 0; s < 4; ++s) {
                    for (int i = lane; i < (int)nbs[s]; i += 64) {
                        unsigned kk = candk[s][i];
                        if ((kk & kmask) == prefix) found = kk;
                    }
                }
                #pragma unroll
                for (int off = 32; off; off >>= 1) found |= (unsigned)__shfl_xor((int)found, off);
                prefix = found;
            }
            if (lane == 0) sh_thresh = __uint_as_float(prefix);
        }
    } else {
        // Generic fallback (never hot): wave 0 full-row radix on flipped keys
        if (wid == 0) {
            unsigned prefix = 0u, kr = (unsigned)k, cnt = 0u;
            for (int p = 0; p < 4; ++p) {
                const int shift = 24 - 8 * p;
                const unsigned pmask = p ? (0xFFFFFFFFu << (shift + 8)) : 0u;
                *(uint4*)&hist[4 * lane] = make_uint4(0u, 0u, 0u, 0u);
                for (int it = 0; it < NIT4; ++it) {
                    const int j4 = it * 64 + lane;
                    if (j4 < C4) {
                        float4 f = lrow4[j4];
                        unsigned kk;
                        kk = flip_key(f.x); if ((kk & pmask) == prefix) atomicAdd(&hist[(kk >> shift) & 0xFFu], 1u);
                        kk = flip_key(f.y); if ((kk & pmask) == prefix) atomicAdd(&hist[(kk >> shift) & 0xFFu], 1u);
                        kk = flip_key(f.z); if ((kk & pmask) == prefix) atomicAdd(&hist[(kk >> shift) & 0xFFu], 1u);
                        kk = flip_key(f.w); if ((kk & pmask) == prefix) atomicAdd(&hist[(kk >> shift) & 0xFFu], 1u);
                    }
                }
                uint4 hv = *(const uint4*)&hist[4 * lane];
                wave_pick(hv, lane, shift, prefix, kr, cnt);
            }
            if (lane == 0) sh_thresh = unflip_key(prefix);
        }
    }
    __syncthreads();                             // ---- B2
    const float thresh = sh_thresh;

    const bool rare = fabsf(madjB) > 80.f;       // exp(adj) over/underflow guard
    float sm = 0.f;
    if (!rare) {
        if (path == 0) {
            // masked set is a subset of this wave's own candidates
            const int nc = (int)sh_nb[wid];
            for (int i = lane; i < nc; i += 64) {
                const float v = __uint_as_float(ck[i]);
                if (v >= thresh) sm += __expf(v + TAU * lcn[ci[i]]);
            }
        } else {
            for (int it = 0; it < ITQ; ++it) {
                const int j4l = it * 64 + lane;
                if (j4l < SEGQ) {
                    float4 f = lrow4[base4 + j4l];
                    float4 l = lcn4[base4 + j4l];
                    if (f.x >= thresh) sm += __expf(f.x + TAU * l.x);
                    if (f.y >= thresh) sm += __expf(f.y + TAU * l.y);
                    if (f.z >= thresh) sm += __expf(f.z + TAU * l.z);
                    if (f.w >= thresh) sm += __expf(f.w + TAU * l.w);
                }
            }
        }
    } else {
        // exact re-sweep of own quarter with max subtraction (never hot)
        z = 0.f;
        for (int it = 0; it < ITQ; ++it) {
            const int j4l = it * 64 + lane;
            if (j4l < SEGQ) {
                float4 f = lrow4[base4 + j4l];
                float4 l = lcn4[base4 + j4l];
                float e;
                e = __expf(f.x + TAU * l.x - madjB); z += e; if (f.x >= thresh) sm += e;
                e = __expf(f.y + TAU * l.y - madjB); z += e; if (f.y >= thresh) sm += e;
                e = __expf(f.z + TAU * l.z - madjB); z += e; if (f.z >= thresh) sm += e;
                e = __expf(f.w + TAU * l.w - madjB); z += e; if (f.w >= thresh) sm += e;
            }
        }
    }

    // ---- Joint reduction of z, sm: wave-level shuffles, then 4 values via LDS
    #pragma unroll
    for (int off = 32; off; off >>= 1) {
        z  += __shfl_down(z, off);
        sm += __shfl_down(sm, off);
    }
    if (lane == 0) { red_a[wid] = z; red_b[wid] = sm; }
    __syncthreads();                             // ---- B3

    if (tid == 0) {
        const float Z = red_a[0] + red_a[1] + red_a[2] + red_a[3];
        const float S = red_b[0] + red_b[1] + red_b[2] + red_b[3];
        const float adj_t = logit_t + TAU * lcn_t;
        const float sub = rare ? madjB : 0.f;
        const float lpt = adj_t - sub - __logf(Z);             // log_p_adj[target]
        const float p_num = ((logit_t >= thresh) ? __expf(lpt) : 0.f) + 1e-6f;
        const float Smask = S / Z + (float)C_DIM * 1e-6f;
        const float loss = 0.5f * (-lpt + __logf(Smask) - __logf(p_num));
        if (part) {
            // 256 line-padded slots: 16 blocks/slot -> parallel across L2 banks
            atomicAdd(&part[(row & (NSLOT - 1)) * SLOT_STRIDE], loss / (float)B);
        } else {
            atomicAdd(out, loss / (float)B);     // fallback: no workspace
        }
    }
}

extern "C" void kernel_launch(void* const* d_in, const int* in_sizes, int n_in,
                              void* d_out, int out_size, void* d_ws, size_t ws_size,
                              hipStream_t stream) {
    const float* logit  = (const float*)d_in[0];
    const int*   target = (const int*)d_in[1];
    const float* lcn    = (const float*)d_in[2];
    const int*   kpc    = (const int*)d_in[3];
    float* out = (float*)d_out;
    const int B = in_sizes[1];   // target is [B]

    const int np = NSLOT * SLOT_STRIDE;          // 4096 floats = 16KB
    float* part = (d_ws != nullptr && ws_size >= (size_t)np * sizeof(float))
                      ? (float*)d_ws : nullptr;

    zero_out_kernel<<<(np + 255) / 256, 256, 0, stream>>>(out, out_size, part, np);
    topk_la_loss_kernel<<<B, BLOCK, 0, stream>>>(logit, target, lcn, kpc, out, part, B);
    if (part) reduce_out_kernel<<<1, 64, 0, stream>>>(part, out);
}